// Round 7
// baseline (19764.592 us; speedup 1.0000x reference)
//
#include <hip/hip_runtime.h>
#include <math.h>

#define B_   32
#define INS  1000
#define TS   999           // recurrent steps computed (t = 0..998)
#define D_   128
#define U_   512
#define G3   1536
#define OUTS 100
#define NB   192           // 64 L0 + 64 L1 + 64 L2 (LX folded into L0)
#define NTICK 1001         // layer j computes t = T - j
#define NTHR 512

// ws layout (floats)
#define HBUF_OFF 0                       // [2][3][512][32]  (parity, layer, k, e)
#define HBUF_SZ  (2*3*512*32)            // 98304
#define BAR_OFF  HBUF_SZ                 // 1024 u32: [0]=flag, [32]=root, [64+g*32]=leaf g

// LDS layout (floats):
//   L1/L2 weights: 8 chunks * (128*24 + 8) = 24640
//   L0   weights: 8 chunks * (80*24 + 8)  = 15424   (64 U0-rows + 16 W0-rows per chunk)
//   L0 xbuf @15424: 2 x [128][32] = 8192  (x staged [k][e], double-buffered)
//   part @24640: [q](968): [g][c][e_pad40] = 7744
//   xpart @32384 (L0 only): [q][c][e_pad40] = 2560  (x-side h-gate partials)
#define W_CHK1  3080
#define W_CHK0  1928
#define XBUF_OFF 15424
#define PART_OFF 24640
#define XPART_OFF 32384
#define SMEM_FLOATS 34944
#define PIDX3(q,g,c,e) ((q)*968 + ((g)*8+(c))*40 + (e))

typedef unsigned long long ull_t;

// Coherent (L1/L2-bypassing) loads: relaxed agent-scope atomics. r5/r6's relaxed
// agent flag polls observed remote stores with no fence -> these bypass stale caches.
__device__ __forceinline__ float4 ld_cg16(const float* p) {
  union { float4 v; ull_t u[2]; } r;
  r.u[0] = __hip_atomic_load((const ull_t*)p,     __ATOMIC_RELAXED, __HIP_MEMORY_SCOPE_AGENT);
  r.u[1] = __hip_atomic_load((const ull_t*)p + 1, __ATOMIC_RELAXED, __HIP_MEMORY_SCOPE_AGENT);
  return r.v;
}
__device__ __forceinline__ float ld_cg4(const float* p) {
  union { float f; unsigned u; } r;
  r.u = __hip_atomic_load((const unsigned*)p, __ATOMIC_RELAXED, __HIP_MEMORY_SCOPE_AGENT);
  return r.f;
}
// write-through store to coherence point
#define WT_STORE(p, v) __hip_atomic_store((p), (v), __ATOMIC_RELAXED, __HIP_MEMORY_SCOPE_AGENT)

#define FMA12() \
  acc[0][0]=fmaf(av.x,w0,acc[0][0]); acc[0][1]=fmaf(av.y,w0,acc[0][1]); \
  acc[0][2]=fmaf(av.z,w0,acc[0][2]); acc[0][3]=fmaf(av.w,w0,acc[0][3]); \
  acc[1][0]=fmaf(av.x,w1,acc[1][0]); acc[1][1]=fmaf(av.y,w1,acc[1][1]); \
  acc[1][2]=fmaf(av.z,w1,acc[1][2]); acc[1][3]=fmaf(av.w,w1,acc[1][3]); \
  acc[2][0]=fmaf(av.x,w2,acc[2][0]); acc[2][1]=fmaf(av.y,w2,acc[2][1]); \
  acc[2][2]=fmaf(av.z,w2,acc[2][2]); acc[2][3]=fmaf(av.w,w2,acc[2][3]);

#define LDC16(DST, PTR) { _Pragma("unroll") \
  for (int t_ = 0; t_ < 16; ++t_) DST[t_] = ld_cg16((PTR) + t_*32); }

#define FMA16(BUF) { _Pragma("unroll") \
  for (int t_ = 0; t_ < 16; ++t_) { \
    const float w0 = wp[0], w1 = wp[1], w2 = wp[2]; \
    const float4 av = BUF[t_]; \
    FMA12(); \
    wp += 24; } }

__global__ void gru_init_kernel(const float* __restrict__ s0,
                                const float* __restrict__ s1,
                                const float* __restrict__ s2,
                                float* __restrict__ ws) {
  int g = blockIdx.x * 256 + threadIdx.x;
  if (g < 1024) { unsigned* bar = (unsigned*)(ws + BAR_OFF); bar[g] = 0u; }
  // h_j(-1) consumed by layer j at tick T=j with par_prev=(j+1)&1: j0->1, j1->0, j2->1
  for (int i = g; i < 3 * 512 * 32; i += gridDim.x * 256) {
    int which = i / (512 * 32);
    int r = i - which * (512 * 32);
    int k = r >> 5, e = r & 31;
    int par = (which == 1) ? 0 : 1;
    const float* s = (which == 0) ? s0 : ((which == 1) ? s1 : s2);
    ws[HBUF_OFF + par * 49152 + which * 16384 + k * 32 + e] = s[k];
  }
}

// Tree barrier, ZERO cache maintenance: data moves via WT stores (drained by the
// entry __syncthreads' vmcnt wait) and coherent sc-loads on the consumer side,
// so arrivals/flag/poll are all RELAXED and no fence is needed in the loop.
__device__ __forceinline__ void gbar(unsigned* bar, unsigned ep, int grp) {
  __syncthreads();
  if (threadIdx.x == 0) {
    unsigned lp = __hip_atomic_fetch_add(&bar[64 + grp * 32], 1u,
                                         __ATOMIC_RELAXED, __HIP_MEMORY_SCOPE_AGENT);
    if (lp == ep * 24u - 1u) {
      unsigned rp = __hip_atomic_fetch_add(&bar[32], 1u,
                                           __ATOMIC_RELAXED, __HIP_MEMORY_SCOPE_AGENT);
      if (rp == ep * 8u - 1u) {
        __hip_atomic_store(&bar[0], ep, __ATOMIC_RELAXED, __HIP_MEMORY_SCOPE_AGENT);
      }
    }
    while (__hip_atomic_load(&bar[0], __ATOMIC_RELAXED, __HIP_MEMORY_SCOPE_AGENT) < ep) {
      __builtin_amdgcn_s_sleep(1);
    }
  }
  __syncthreads();
}

__global__ __launch_bounds__(NTHR, 1) void gru_persist(
    const float* __restrict__ x,
    const float* __restrict__ W0c, const float* __restrict__ U0c, const float* __restrict__ b0c,
    const float* __restrict__ W1c, const float* __restrict__ U1c, const float* __restrict__ b1c,
    const float* __restrict__ W2c, const float* __restrict__ U2c, const float* __restrict__ b2c,
    const float* __restrict__ Wd, const float* __restrict__ bd,
    float* __restrict__ out, float* __restrict__ ws)
{
  float* hbuf = ws + HBUF_OFF;
  unsigned* bar = (unsigned*)(ws + BAR_OFF);
  float* pred_out = out;                       // [32][100][128]
  float* hid_out  = out + B_ * OUTS * D_;      // [32][100][3][512]

  const int bid = blockIdx.x;
  const int tid = threadIdx.x;
  const int grp = bid & 7;

  const int role = bid >> 6;                   // 0,1,2 = layer
  const int rb   = bid & 63;

  __shared__ float smem[SMEM_FLOATS];          // 136.5 KiB
  float* part = smem + PART_OFF;

  // GEMM mapping: wave = K-chunk q; lanes: eg (low 3b) spans a 128B A-row,
  // c_l (mid 3b) selects the LDS weight column (same-address A dup = free).
  const int eg  = tid & 7;
  const int c_l = (tid >> 3) & 7;
  const int q   = tid >> 6;
  // XCD-locality col swizzle
  const int cb  = (rb & 7) * 8 + (rb >> 3);
  const int c0  = cb * 8;
  // reduce/elementwise mapping (tid < 256)
  const int rc = tid >> 5;
  const int re = tid & 31;
  // L0 x-staging mapping
  const int xe  = tid >> 4;          // batch elem 0..31
  const int xd8 = (tid & 15) * 8;    // 8 consecutive d

  const float *Wj = nullptr, *Ujp = nullptr, *bj = nullptr;
  if      (role == 0) { Wj = W0c; Ujp = U0c; bj = b0c; }
  else if (role == 1) { Wj = W1c; Ujp = U1c; bj = b1c; }
  else                { Wj = W2c; Ujp = U2c; bj = b2c; }

  // ---- one-time staging ----
  if (role == 0) {
    // chunk q = 64 U0-rows (q*64..) then 16 W0-rows (q*16..)
    for (int idx = tid; idx < 8 * 80 * 24; idx += NTHR) {
      int qq = idx / (80 * 24);
      int r  = idx - qq * (80 * 24);
      int i  = r / 24;
      int cg = r - i * 24;
      int c  = cg / 3, g = cg - c * 3;
      const float* mat; int row;
      if (i < 64) { mat = Ujp; row = qq * 64 + i; }
      else        { mat = Wj;  row = qq * 16 + (i - 64); }
      smem[qq * W_CHK0 + i * 24 + c * 3 + g] = mat[row * G3 + g * 512 + c0 + c];
    }
    // x(0) -> xbuf[0], layout [k][e]
    {
      const float* xs = x + xe * (INS * D_) + xd8;
      union { float4 v; float f[4]; } a, b;
      a.v = *(const float4*)(xs);
      b.v = *(const float4*)(xs + 4);
      #pragma unroll
      for (int kk = 0; kk < 4; ++kk) {
        smem[XBUF_OFF + (xd8 + kk) * 32 + xe]     = a.f[kk];
        smem[XBUF_OFF + (xd8 + 4 + kk) * 32 + xe] = b.f[kk];
      }
    }
  } else {
    for (int idx = tid; idx < 8 * 128 * 24; idx += NTHR) {
      int qq = idx / (128 * 24);
      int r  = idx - qq * (128 * 24);
      int i  = r / 24;
      int cg = r - i * 24;
      int c  = cg / 3, g = cg - c * 3;
      const float* mat; int row;
      if (qq < 4) { mat = Wj;  row = qq * 128 + i; }
      else        { mat = Ujp; row = (qq - 4) * 128 + i; }
      smem[qq * W_CHK1 + i * 24 + c * 3 + g] = mat[row * G3 + g * 512 + c0 + c];
    }
  }
  // bias preload
  float bz = 0.f, br = 0.f, b0h = 0.f, b1h = 0.f;
  if (tid < 256) {
    const int cg2 = c0 + rc;
    bz  = bj[cg2] + bj[G3 + cg2];
    br  = bj[512 + cg2] + bj[G3 + 512 + cg2];
    b0h = bj[1024 + cg2];
    b1h = bj[G3 + 1024 + cg2];
  }
  __syncthreads();

  for (int T = 0; T < NTICK; ++T) {
    const int par_prev = (T + 1) & 1;
    const int par_cur  = T & 1;
    const int j = role;
    const int t = T - j;

    if (t >= 0 && t < TS) {
      const float* hprev_all = hbuf + par_prev * 49152;
      float hp = 0.f;
      if (tid < 256) hp = ld_cg4(hprev_all + j * 16384 + (c0 + rc) * 32 + re);

      float acc[3][4];
      #pragma unroll
      for (int g2 = 0; g2 < 3; ++g2)
        #pragma unroll
        for (int i2 = 0; i2 < 4; ++i2) acc[g2][i2] = 0.f;

      if (j == 0) {
        // x(t+1) prefetch (plain loads; x is read-only -> L2-cacheable, never stale)
        union { float4 v; float f[4]; } xpa, xpb;
        const bool pf = (t + 1) < TS;
        if (pf) {
          const float* xs = x + xe * (INS * D_) + (t + 1) * D_ + xd8;
          xpa.v = *(const float4*)(xs);
          xpb.v = *(const float4*)(xs + 4);
        }
        float accX[4] = {0.f, 0.f, 0.f, 0.f};
        // h-side: 64 rows via coherent loads
        const float* Ab = hprev_all + (q * 64) * 32 + eg * 4;
        const float* wp = smem + q * W_CHK0 + c_l * 3;
        float4 bufA[16], bufB[16], bufC[16];
        LDC16(bufA, Ab);        LDC16(bufB, Ab + 512);
        LDC16(bufC, Ab + 1024); FMA16(bufA);
        LDC16(bufA, Ab + 1536); FMA16(bufB);
        FMA16(bufC);
        FMA16(bufA);
        // x-side: 16 rows from LDS xbuf[t&1]; h-gate goes to accX
        const float* xbq = smem + XBUF_OFF + (t & 1) * 4096 + (q * 16) * 32 + eg * 4;
        #pragma unroll
        for (int i = 0; i < 16; ++i) {
          const float4 av = *(const float4*)(xbq + i * 32);
          const float w0 = wp[0], w1 = wp[1], w2 = wp[2];
          acc[0][0]=fmaf(av.x,w0,acc[0][0]); acc[0][1]=fmaf(av.y,w0,acc[0][1]);
          acc[0][2]=fmaf(av.z,w0,acc[0][2]); acc[0][3]=fmaf(av.w,w0,acc[0][3]);
          acc[1][0]=fmaf(av.x,w1,acc[1][0]); acc[1][1]=fmaf(av.y,w1,acc[1][1]);
          acc[1][2]=fmaf(av.z,w1,acc[1][2]); acc[1][3]=fmaf(av.w,w1,acc[1][3]);
          accX[0]=fmaf(av.x,w2,accX[0]); accX[1]=fmaf(av.y,w2,accX[1]);
          accX[2]=fmaf(av.z,w2,accX[2]); accX[3]=fmaf(av.w,w2,accX[3]);
          wp += 24;
        }
        #pragma unroll
        for (int g2 = 0; g2 < 3; ++g2)
          *(float4*)&part[PIDX3(q, g2, c_l, eg * 4)] =
              make_float4(acc[g2][0], acc[g2][1], acc[g2][2], acc[g2][3]);
        *(float4*)&smem[XPART_OFF + q * 320 + c_l * 40 + eg * 4] =
            make_float4(accX[0], accX[1], accX[2], accX[3]);
        __syncthreads();

        if (tid < 256) {
          float gz = 0.f, gr = 0.f, hh = 0.f, xh = 0.f;
          #pragma unroll
          for (int q2 = 0; q2 < 8; ++q2) {
            gz += part[PIDX3(q2, 0, rc, re)];
            gr += part[PIDX3(q2, 1, rc, re)];
            hh += part[PIDX3(q2, 2, rc, re)];
            xh += smem[XPART_OFF + q2 * 320 + rc * 40 + re];
          }
          const int cg2 = c0 + rc;
          const float z = 1.f / (1.f + expf(-(gz + bz)));
          const float r = 1.f / (1.f + expf(-(gr + br)));
          const float cand = tanhf((xh + b0h) + r * (hh + b1h));
          const float hn = z * hp + (1.f - z) * cand;
          WT_STORE(&hbuf[par_cur * 49152 + 0 * 16384 + cg2 * 32 + re], hn);
          if (t >= TS - OUTS)
            WT_STORE(&hid_out[((re * OUTS + (t - (TS - OUTS))) * 3 + 0) * U_ + cg2], hn);
        }
        // publish prefetched x into xbuf[(t+1)&1] (read next tick after gbar)
        if (pf) {
          float* xw = smem + XBUF_OFF + ((t + 1) & 1) * 4096;
          #pragma unroll
          for (int kk = 0; kk < 4; ++kk) {
            xw[(xd8 + kk) * 32 + xe]     = xpa.f[kk];
            xw[(xd8 + 4 + kk) * 32 + xe] = xpb.f[kk];
          }
        }
      } else {
        // j = 1,2: K=1024 = [h_{j-1} | h_j], all via coherent loads
        const float* Ab = hprev_all + ((q < 4) ? (j - 1) : j) * 16384 + ((q & 3) * 128) * 32 + eg * 4;
        const float* wp = smem + q * W_CHK1 + c_l * 3;
        float4 bufA[16], bufB[16], bufC[16];
        LDC16(bufA, Ab);        LDC16(bufB, Ab + 512);
        LDC16(bufC, Ab + 1024); FMA16(bufA);
        LDC16(bufA, Ab + 1536); FMA16(bufB);
        LDC16(bufB, Ab + 2048); FMA16(bufC);
        LDC16(bufC, Ab + 2560); FMA16(bufA);
        LDC16(bufA, Ab + 3072); FMA16(bufB);
        LDC16(bufB, Ab + 3584); FMA16(bufC);
        FMA16(bufA);
        FMA16(bufB);
        #pragma unroll
        for (int g2 = 0; g2 < 3; ++g2)
          *(float4*)&part[PIDX3(q, g2, c_l, eg * 4)] =
              make_float4(acc[g2][0], acc[g2][1], acc[g2][2], acc[g2][3]);
        __syncthreads();

        if (tid < 256) {
          float gz = 0.f, gr = 0.f, xh = 0.f, hh = 0.f;
          #pragma unroll
          for (int q2 = 0; q2 < 8; ++q2) {
            gz += part[PIDX3(q2, 0, rc, re)];
            gr += part[PIDX3(q2, 1, rc, re)];
            float v = part[PIDX3(q2, 2, rc, re)];
            if (q2 < 4) xh += v; else hh += v;
          }
          const int cg2 = c0 + rc;
          const float z = 1.f / (1.f + expf(-(gz + bz)));
          const float r = 1.f / (1.f + expf(-(gr + br)));
          const float cand = tanhf((xh + b0h) + r * (hh + b1h));
          const float hn = z * hp + (1.f - z) * cand;
          WT_STORE(&hbuf[par_cur * 49152 + j * 16384 + cg2 * 32 + re], hn);
          if (t >= TS - OUTS)
            WT_STORE(&hid_out[((re * OUTS + (t - (TS - OUTS))) * 3 + j) * U_ + cg2], hn);
        }
      }
    }
    gbar(bar, (unsigned)(T + 1), grp);
  }

  // one acquire for the readout (hid_out was WT-written by other blocks;
  // invalidate any stale clean L2 lines from the host-side memset)
  __builtin_amdgcn_fence(__ATOMIC_ACQUIRE, "agent");

  // readout: pred[b][s][dd] = ys[b][s] @ Wd + bd   (ys = hidden[...,2,:])
  const int gt = bid * NTHR + tid;
  for (int o = gt; o < B_ * OUTS * D_; o += NB * NTHR) {
    int b  = o / (OUTS * D_);
    int r2 = o - b * (OUTS * D_);
    int s  = r2 >> 7;
    int dd = r2 & 127;
    const float* ys = hid_out + ((b * OUTS + s) * 3 + 2) * U_;
    float acc = bd[dd];
    #pragma unroll 4
    for (int k = 0; k < U_; k += 4) {
      float4 yv = *(const float4*)(ys + k);
      acc = fmaf(yv.x, Wd[(k    ) * D_ + dd], acc);
      acc = fmaf(yv.y, Wd[(k + 1) * D_ + dd], acc);
      acc = fmaf(yv.z, Wd[(k + 2) * D_ + dd], acc);
      acc = fmaf(yv.w, Wd[(k + 3) * D_ + dd], acc);
    }
    pred_out[o] = acc;
  }
}

extern "C" void kernel_launch(void* const* d_in, const int* in_sizes, int n_in,
                              void* d_out, int out_size, void* d_ws, size_t ws_size,
                              hipStream_t stream) {
  const float* x  = (const float*)d_in[0];
  const float* W0 = (const float*)d_in[1];
  const float* U0 = (const float*)d_in[2];
  const float* b0 = (const float*)d_in[3];
  const float* s0 = (const float*)d_in[4];
  const float* W1 = (const float*)d_in[5];
  const float* U1 = (const float*)d_in[6];
  const float* b1 = (const float*)d_in[7];
  const float* s1 = (const float*)d_in[8];
  const float* W2 = (const float*)d_in[9];
  const float* U2 = (const float*)d_in[10];
  const float* b2 = (const float*)d_in[11];
  const float* s2 = (const float*)d_in[12];
  const float* Wd = (const float*)d_in[13];
  const float* bd = (const float*)d_in[14];
  float* ws = (float*)d_ws;

  gru_init_kernel<<<192, 256, 0, stream>>>(s0, s1, s2, ws);
  gru_persist<<<NB, NTHR, 0, stream>>>(x, W0, U0, b0, W1, U1, b1,
                                       W2, U2, b2, Wd, bd, (float*)d_out, ws);
}

// Round 8
// 12650.056 us; speedup vs baseline: 1.5624x; 1.5624x over previous
//
#include <hip/hip_runtime.h>
#include <math.h>

#define B_   32
#define INS  1000
#define TS   999           // recurrent steps computed (t = 0..998)
#define D_   128
#define U_   512
#define G3   1536
#define OUTS 100
#define NB   208           // persistent grid: 16 LX + 64 L0 + 64 L1 + 64 L2
#define NTICK 1002         // LX: T=t (0..998); layer j computes t = T-(j+1)
#define NTHR 1024

// ws layout (floats)
#define HBUF_OFF 0                       // [2][3][512][32]  (parity, layer, k, e)
#define HBUF_SZ  (2*3*512*32)            // 98304
#define RING_OFF HBUF_SZ                 // [4][1536][32]    mx0 ring
#define RING_SZ  (4*1536*32)             // 196608
#define BAR_OFF  (RING_OFF + RING_SZ)    // barrier state: 1024 u32
// bar[0]=epoch flag, bar[32]=root counter, bar[64+g*32]=leaf counter g (8 leaves, bid&7)

// LDS layout (floats):
//   L1/L2 weights: 16 chunks * (64*24 + 8) = 16*1544 = 24704
//   L0   weights: 16 chunks * (32*24 + 8) = 16*776  = 12416
//   LX: W0 slice [128][96] = 12288 @ 0; x dbuf 2*[32][128] = 8192 @ 12288
//   part @ 24704: [q=16](968): [g][c][e_pad40] = 15488
#define W_CHK1  1544
#define W_CHK0  776
#define XBUF_OFF 12288
#define PART_OFF 24704
#define SMEM_FLOATS 40192
#define PIDX3(q,g,c,e) ((q)*968 + ((g)*8+(c))*40 + (e))

// write-through store to coherence point (no dirty L2 line -> no wbl2 at barrier)
#define WT_STORE(p, v) __hip_atomic_store((p), (v), __ATOMIC_RELAXED, __HIP_MEMORY_SCOPE_AGENT)

#define FMA12() \
  acc[0][0]=fmaf(av.x,w0,acc[0][0]); acc[0][1]=fmaf(av.y,w0,acc[0][1]); \
  acc[0][2]=fmaf(av.z,w0,acc[0][2]); acc[0][3]=fmaf(av.w,w0,acc[0][3]); \
  acc[1][0]=fmaf(av.x,w1,acc[1][0]); acc[1][1]=fmaf(av.y,w1,acc[1][1]); \
  acc[1][2]=fmaf(av.z,w1,acc[1][2]); acc[1][3]=fmaf(av.w,w1,acc[1][3]); \
  acc[2][0]=fmaf(av.x,w2,acc[2][0]); acc[2][1]=fmaf(av.y,w2,acc[2][1]); \
  acc[2][2]=fmaf(av.z,w2,acc[2][2]); acc[2][3]=fmaf(av.w,w2,acc[2][3]);

#define LD16(DST, PTR) { _Pragma("unroll") \
  for (int t_ = 0; t_ < 16; ++t_) DST[t_] = *(const float4*)((PTR) + t_*32); }

#define FMA16(BUF) { _Pragma("unroll") \
  for (int t_ = 0; t_ < 16; ++t_) { \
    const float w0 = wp[0], w1 = wp[1], w2 = wp[2]; \
    const float4 av = BUF[t_]; \
    FMA12(); \
    wp += 24; } }

__global__ void gru_init_kernel(const float* __restrict__ s0,
                                const float* __restrict__ s1,
                                const float* __restrict__ s2,
                                float* __restrict__ ws) {
  int g = blockIdx.x * 256 + threadIdx.x;
  if (g < 1024) { unsigned* bar = (unsigned*)(ws + BAR_OFF); bar[g] = 0u; }
  // h_j(-1): layer j first computes at T=j+1 with par_prev=(j+2)&1: j0->0, j1->1, j2->0
  for (int i = g; i < 3 * 512 * 32; i += gridDim.x * 256) {
    int which = i / (512 * 32);
    int r = i - which * (512 * 32);
    int k = r >> 5, e = r & 31;
    int par = (which == 1) ? 1 : 0;
    const float* s = (which == 0) ? s0 : ((which == 1) ? s1 : s2);
    ws[HBUF_OFF + par * 49152 + which * 16384 + k * 32 + e] = s[k];
  }
}

// Tree barrier: data moved via WT stores (drained by the entry __syncthreads'
// vmcnt wait) -> arrivals/flag RELAXED (no wbl2). ONE acquire (buffer_inv) per
// tick after the flag flips; L2 then refills ~940KB/tick from L3 (measured).
__device__ __forceinline__ void gbar(unsigned* bar, unsigned ep, int grp) {
  __syncthreads();
  if (threadIdx.x == 0) {
    unsigned lp = __hip_atomic_fetch_add(&bar[64 + grp * 32], 1u,
                                         __ATOMIC_RELAXED, __HIP_MEMORY_SCOPE_AGENT);
    if (lp == ep * 26u - 1u) {
      unsigned rp = __hip_atomic_fetch_add(&bar[32], 1u,
                                           __ATOMIC_RELAXED, __HIP_MEMORY_SCOPE_AGENT);
      if (rp == ep * 8u - 1u) {
        __hip_atomic_store(&bar[0], ep, __ATOMIC_RELAXED, __HIP_MEMORY_SCOPE_AGENT);
      }
    }
    while (__hip_atomic_load(&bar[0], __ATOMIC_RELAXED, __HIP_MEMORY_SCOPE_AGENT) < ep) {
      __builtin_amdgcn_s_sleep(1);
    }
    __builtin_amdgcn_fence(__ATOMIC_ACQUIRE, "agent");
  }
  __syncthreads();
}

__global__ __launch_bounds__(NTHR, 1) void gru_persist(
    const float* __restrict__ x,
    const float* __restrict__ W0c, const float* __restrict__ U0c, const float* __restrict__ b0c,
    const float* __restrict__ W1c, const float* __restrict__ U1c, const float* __restrict__ b1c,
    const float* __restrict__ W2c, const float* __restrict__ U2c, const float* __restrict__ b2c,
    const float* __restrict__ Wd, const float* __restrict__ bd,
    float* __restrict__ out, float* __restrict__ ws)
{
  float* hbuf = ws + HBUF_OFF;
  float* ring = ws + RING_OFF;
  unsigned* bar = (unsigned*)(ws + BAR_OFF);
  float* pred_out = out;                       // [32][100][128]
  float* hid_out  = out + B_ * OUTS * D_;      // [32][100][3][512]

  const int bid = blockIdx.x;
  const int tid = threadIdx.x;
  const int grp = bid & 7;

  int role, rb;
  if      (bid < 16)  { role = -1; rb = bid; }
  else if (bid < 80)  { role = 0;  rb = bid - 16; }
  else if (bid < 144) { role = 1;  rb = bid - 80; }
  else                { role = 2;  rb = bid - 144; }

  __shared__ float smem[SMEM_FLOATS];     // 157 KiB
  float* part = smem + PART_OFF;

  // GEMM mapping: wave = K-chunk q (tid>>6, 0..15). Within wave: eg spans one
  // 128B A-row (coalesced); c_l picks the LDS weight column (A dup = free).
  const int eg  = tid & 7;
  const int c_l = (tid >> 3) & 7;
  const int q   = tid >> 6;
  // XCD-locality col swizzle
  const int cb  = (rb & 7) * 8 + (rb >> 3);
  const int c0  = cb * 8;
  // reduce/elementwise mapping (tid < 256)
  const int rc = tid >> 5;
  const int re = tid & 31;
  // LX mapping (compute phase uses tid<512; prefetch uses all 1024)
  const int xb0 = ((rb & 7) * 2 + (rb >> 3)) * 96;
  const int cg3 = (tid & 31) * 3;
  const int e0  = (tid >> 5) * 2;
  const int xe  = tid >> 5;          // 0..31 (x prefetch: one float4/thread)
  const int xd4 = (tid & 31) * 4;

  const float *Wj = nullptr, *Ujp = nullptr, *bj = nullptr;
  if      (role == 0) { Ujp = U0c; bj = b0c; }
  else if (role == 1) { Wj = W1c; Ujp = U1c; bj = b1c; }
  else if (role == 2) { Wj = W2c; Ujp = U2c; bj = b2c; }

  // ---- one-time staging ----
  if (role < 0) {
    for (int idx = tid; idx < 128 * 96; idx += NTHR)
      smem[idx] = W0c[(idx / 96) * G3 + xb0 + (idx % 96)];
    // x(0) -> xbuf[0], [e][128]
    *(float4*)(smem + XBUF_OFF + xe * 128 + xd4) =
        *(const float4*)(x + xe * (INS * D_) + xd4);
  } else if (role == 0) {
    // 16 chunks x 32 U0-rows
    for (int idx = tid; idx < 16 * 32 * 24; idx += NTHR) {
      int qq = idx / (32 * 24);
      int r  = idx - qq * (32 * 24);
      int i  = r / 24;
      int cg = r - i * 24;
      int c  = cg / 3, g = cg - c * 3;
      smem[qq * W_CHK0 + i * 24 + c * 3 + g] = Ujp[(qq * 32 + i) * G3 + g * 512 + c0 + c];
    }
  } else {
    // 16 chunks x 64 rows: qq<8 -> W rows qq*64.., else U rows (qq-8)*64..
    for (int idx = tid; idx < 16 * 64 * 24; idx += NTHR) {
      int qq = idx / (64 * 24);
      int r  = idx - qq * (64 * 24);
      int i  = r / 24;
      int cg = r - i * 24;
      int c  = cg / 3, g = cg - c * 3;
      const float* mat; int row;
      if (qq < 8) { mat = Wj;  row = qq * 64 + i; }
      else        { mat = Ujp; row = (qq - 8) * 64 + i; }
      smem[qq * W_CHK1 + i * 24 + c * 3 + g] = mat[row * G3 + g * 512 + c0 + c];
    }
  }
  float bz = 0.f, br = 0.f, b0h = 0.f, b1h = 0.f;
  if (role >= 0 && tid < 256) {
    const int cg2 = c0 + rc;
    bz  = bj[cg2] + bj[G3 + cg2];
    br  = bj[512 + cg2] + bj[G3 + 512 + cg2];
    b0h = bj[1024 + cg2];
    b1h = bj[G3 + 1024 + cg2];
  }
  __syncthreads();

  for (int T = 0; T < NTICK; ++T) {
    const int par_prev = (T + 1) & 1;
    const int par_cur  = T & 1;

    if (role < 0) {
      const int t = T;
      if (t < TS) {
        // (a) prefetch x(t+1) -> regs (one float4 per thread)
        float4 xp;
        const bool pf = (t + 1) < TS;
        if (pf)
          xp = *(const float4*)(x + xe * (INS * D_) + (t + 1) * D_ + xd4);
        // (b) compute mx0(t) from xbuf[t&1] (512 threads)
        if (tid < 512) {
          const float* xb = smem + XBUF_OFF + (t & 1) * 4096;
          float acc[3][2];
          #pragma unroll
          for (int c = 0; c < 3; ++c) { acc[c][0] = 0.f; acc[c][1] = 0.f; }
          #pragma unroll 4
          for (int k4 = 0; k4 < D_; k4 += 4) {
            float4 v0 = *(const float4*)(xb + e0 * 128 + k4);
            float4 v1 = *(const float4*)(xb + (e0 + 1) * 128 + k4);
            float xs0[4] = {v0.x, v0.y, v0.z, v0.w};
            float xs1[4] = {v1.x, v1.y, v1.z, v1.w};
            #pragma unroll
            for (int kk = 0; kk < 4; ++kk) {
              const float* wpx = smem + (k4 + kk) * 96 + cg3;
              float w0 = wpx[0], w1 = wpx[1], w2 = wpx[2];
              acc[0][0] = fmaf(xs0[kk], w0, acc[0][0]);
              acc[0][1] = fmaf(xs1[kk], w0, acc[0][1]);
              acc[1][0] = fmaf(xs0[kk], w1, acc[1][0]);
              acc[1][1] = fmaf(xs1[kk], w1, acc[1][1]);
              acc[2][0] = fmaf(xs0[kk], w2, acc[2][0]);
              acc[2][1] = fmaf(xs1[kk], w2, acc[2][1]);
            }
          }
          float* dst = ring + (t & 3) * (G3 * 32);
          #pragma unroll
          for (int c = 0; c < 3; ++c) {
            WT_STORE(dst + (xb0 + cg3 + c) * 32 + e0,     acc[c][0]);
            WT_STORE(dst + (xb0 + cg3 + c) * 32 + e0 + 1, acc[c][1]);
          }
        }
        // (c) publish prefetched x into xbuf[(t+1)&1]
        if (pf) {
          __syncthreads();
          *(float4*)(smem + XBUF_OFF + ((t + 1) & 1) * 4096 + xe * 128 + xd4) = xp;
        }
      }
    } else {
      const int j = role;
      const int t = T - (j + 1);
      if (t >= 0 && t < TS) {
        const float* hprev_all = hbuf + par_prev * 49152;
        float xz = 0.f, xr2 = 0.f, xhv0 = 0.f, hp = 0.f;
        if (tid < 256) {
          const int cg2 = c0 + rc;
          hp = hprev_all[j * 16384 + cg2 * 32 + re];
          if (j == 0) {
            const float* r3 = ring + (t & 3) * (G3 * 32);
            xz   = r3[cg2 * 32 + re];
            xr2  = r3[(512 + cg2) * 32 + re];
            xhv0 = r3[(1024 + cg2) * 32 + re];
          }
        }

        float acc[3][4];
        #pragma unroll
        for (int g2 = 0; g2 < 3; ++g2)
          #pragma unroll
          for (int i2 = 0; i2 < 4; ++i2) acc[g2][i2] = 0.f;

        float4 bufA[16], bufB[16], bufC[16];
        if (j == 0) {
          // 32 rows per chunk
          const float* Ab = hprev_all + q * 1024 + eg * 4;
          const float* wp = smem + q * W_CHK0 + c_l * 3;
          LD16(bufA, Ab); LD16(bufB, Ab + 512);
          FMA16(bufA);
          FMA16(bufB);
        } else {
          // 64 rows per chunk: q<8 -> x-side (h_{j-1}), else h-side (h_j)
          const float* Ab = hprev_all + ((q < 8) ? (j - 1) : j) * 16384 + ((q & 7) * 64) * 32 + eg * 4;
          const float* wp = smem + q * W_CHK1 + c_l * 3;
          LD16(bufA, Ab);        LD16(bufB, Ab + 512);
          LD16(bufC, Ab + 1024); FMA16(bufA);
          LD16(bufA, Ab + 1536); FMA16(bufB);
          FMA16(bufC);
          FMA16(bufA);
        }
        #pragma unroll
        for (int g2 = 0; g2 < 3; ++g2)
          *(float4*)&part[PIDX3(q, g2, c_l, eg * 4)] =
              make_float4(acc[g2][0], acc[g2][1], acc[g2][2], acc[g2][3]);
        __syncthreads();

        if (tid < 256) {
          float gz = 0.f, gr = 0.f, xh = 0.f, hh = 0.f;
          #pragma unroll
          for (int q2 = 0; q2 < 16; ++q2) {
            gz += part[PIDX3(q2, 0, rc, re)];
            gr += part[PIDX3(q2, 1, rc, re)];
            float v = part[PIDX3(q2, 2, rc, re)];
            if (j == 0)       hh += v;
            else if (q2 < 8)  xh += v;
            else              hh += v;
          }
          const int cg2 = c0 + rc;
          const float xhv = (j == 0) ? xhv0 : xh;
          const float zi = gz + xz + bz;
          const float ri = gr + xr2 + br;
          const float z = 1.f / (1.f + expf(-zi));
          const float r = 1.f / (1.f + expf(-ri));
          const float cand = tanhf((xhv + b0h) + r * (hh + b1h));
          const float hn = z * hp + (1.f - z) * cand;
          WT_STORE(&hbuf[par_cur * 49152 + j * 16384 + cg2 * 32 + re], hn);
          if (t >= TS - OUTS) {
            WT_STORE(&hid_out[((re * OUTS + (t - (TS - OUTS))) * 3 + j) * U_ + cg2], hn);
          }
        }
      }
    }
    gbar(bar, (unsigned)(T + 1), grp);
  }

  // readout: pred[b][s][dd] = ys[b][s] @ Wd + bd   (ys = hidden[...,2,:])
  const int gt = bid * NTHR + tid;
  for (int o = gt; o < B_ * OUTS * D_; o += NB * NTHR) {
    int b  = o / (OUTS * D_);
    int r2 = o - b * (OUTS * D_);
    int s  = r2 >> 7;
    int dd = r2 & 127;
    const float* ys = hid_out + ((b * OUTS + s) * 3 + 2) * U_;
    float acc = bd[dd];
    #pragma unroll 4
    for (int k = 0; k < U_; k += 4) {
      float4 yv = *(const float4*)(ys + k);
      acc = fmaf(yv.x, Wd[(k    ) * D_ + dd], acc);
      acc = fmaf(yv.y, Wd[(k + 1) * D_ + dd], acc);
      acc = fmaf(yv.z, Wd[(k + 2) * D_ + dd], acc);
      acc = fmaf(yv.w, Wd[(k + 3) * D_ + dd], acc);
    }
    pred_out[o] = acc;
  }
}

extern "C" void kernel_launch(void* const* d_in, const int* in_sizes, int n_in,
                              void* d_out, int out_size, void* d_ws, size_t ws_size,
                              hipStream_t stream) {
  const float* x  = (const float*)d_in[0];
  const float* W0 = (const float*)d_in[1];
  const float* U0 = (const float*)d_in[2];
  const float* b0 = (const float*)d_in[3];
  const float* s0 = (const float*)d_in[4];
  const float* W1 = (const float*)d_in[5];
  const float* U1 = (const float*)d_in[6];
  const float* b1 = (const float*)d_in[7];
  const float* s1 = (const float*)d_in[8];
  const float* W2 = (const float*)d_in[9];
  const float* U2 = (const float*)d_in[10];
  const float* b2 = (const float*)d_in[11];
  const float* s2 = (const float*)d_in[12];
  const float* Wd = (const float*)d_in[13];
  const float* bd = (const float*)d_in[14];
  float* ws = (float*)d_ws;

  gru_init_kernel<<<192, 256, 0, stream>>>(s0, s1, s2, ws);
  gru_persist<<<NB, NTHR, 0, stream>>>(x, W0, U0, b0, W1, U1, b1,
                                       W2, U2, b2, Wd, bd, (float*)d_out, ws);
}

// Round 9
// 10839.144 us; speedup vs baseline: 1.8234x; 1.1671x over previous
//
#include <hip/hip_runtime.h>
#include <math.h>

#define B_   32
#define INS  1000
#define TS   999           // recurrent steps computed (t = 0..998)
#define D_   128
#define U_   512
#define G3   1536
#define OUTS 100
#define NB   208           // persistent grid: 16 LX + 64 L0 + 64 L1 + 64 L2
#define NTICK 1002         // LX: T=t (0..998); layer j computes t = T-(j+1)
#define NTHR 512

// ws layout (floats)
#define HBUF_OFF 0                       // [2][3][512][32]  (parity, layer, k, e)
#define HBUF_SZ  (2*3*512*32)            // 98304
#define RING_OFF HBUF_SZ                 // [4][1536][32]    mx0 ring
#define RING_SZ  (4*1536*32)             // 196608
#define BAR_OFF  (RING_OFF + RING_SZ)    // barrier state: 4096 u32
// bar[0] = epoch flag; bar[256 + bid*16] = per-block arrival slot (64B apart)

// LDS layout (floats):
//   L1/L2 weights: 8 chunks * (128*24 + 8) = 24640
//   L0   weights: 8 chunks * (64*24 + 8)  = 12352
//   LX: W0 slice [128][96] = 12288 @ 0; x dbuf 2*[32][128] = 8192 @ 12288
//   part @ 24640: [q](968): [g][c][e_pad40] = 7744
#define W_CHK1  3080
#define W_CHK0  1544
#define XBUF_OFF 12288
#define PART_OFF 24640
#define SMEM_FLOATS 32384
#define PIDX3(q,g,c,e) ((q)*968 + ((g)*8+(c))*40 + (e))

// write-through store to coherence point (no dirty L2 line -> no wbl2 at barrier)
#define WT_STORE(p, v) __hip_atomic_store((p), (v), __ATOMIC_RELAXED, __HIP_MEMORY_SCOPE_AGENT)
#define CG_LOAD(p)     __hip_atomic_load((p), __ATOMIC_RELAXED, __HIP_MEMORY_SCOPE_AGENT)

#define FMA12() \
  acc[0][0]=fmaf(av.x,w0,acc[0][0]); acc[0][1]=fmaf(av.y,w0,acc[0][1]); \
  acc[0][2]=fmaf(av.z,w0,acc[0][2]); acc[0][3]=fmaf(av.w,w0,acc[0][3]); \
  acc[1][0]=fmaf(av.x,w1,acc[1][0]); acc[1][1]=fmaf(av.y,w1,acc[1][1]); \
  acc[1][2]=fmaf(av.z,w1,acc[1][2]); acc[1][3]=fmaf(av.w,w1,acc[1][3]); \
  acc[2][0]=fmaf(av.x,w2,acc[2][0]); acc[2][1]=fmaf(av.y,w2,acc[2][1]); \
  acc[2][2]=fmaf(av.z,w2,acc[2][2]); acc[2][3]=fmaf(av.w,w2,acc[2][3]);

#define LD16(DST, PTR) { _Pragma("unroll") \
  for (int t_ = 0; t_ < 16; ++t_) DST[t_] = *(const float4*)((PTR) + t_*32); }

#define FMA16(BUF) { _Pragma("unroll") \
  for (int t_ = 0; t_ < 16; ++t_) { \
    const float w0 = wp[0], w1 = wp[1], w2 = wp[2]; \
    const float4 av = BUF[t_]; \
    FMA12(); \
    wp += 24; } }

__global__ void gru_init_kernel(const float* __restrict__ s0,
                                const float* __restrict__ s1,
                                const float* __restrict__ s2,
                                float* __restrict__ ws) {
  int g = blockIdx.x * 256 + threadIdx.x;
  if (g < 4096) { unsigned* bar = (unsigned*)(ws + BAR_OFF); bar[g] = 0u; }
  for (int i = g; i < 3 * 512 * 32; i += gridDim.x * 256) {
    int which = i / (512 * 32);
    int r = i - which * (512 * 32);
    int k = r >> 5, e = r & 31;
    int par = (which == 1) ? 1 : 0;
    const float* s = (which == 0) ? s0 : ((which == 1) ? s1 : s2);
    ws[HBUF_OFF + par * 49152 + which * 16384 + k * 32 + e] = s[k];
  }
}

// Zero-RMW barrier. Arrival: ONE relaxed WT store to the block's PRIVATE slot
// (no atomic RMW, no same-address serialization; h-data already at the
// coherence point because the entry __syncthreads drains vmcnt of WT stores).
// Detection: block 0's threads 0..NB-1 poll one slot each IN PARALLEL, then
// thread 0 publishes the epoch flag. All blocks poll the flag (1 load/round),
// then issue ONE agent acquire (buffer_inv) for the tick's fresh data.
__device__ __forceinline__ void gbar(unsigned* bar, unsigned ep, int bid) {
  __syncthreads();
  const int tid = threadIdx.x;
  if (tid == 0) WT_STORE(&bar[256 + bid * 16], ep);
  if (bid == 0) {
    if (tid < NB) {
      while (CG_LOAD(&bar[256 + tid * 16]) < ep) __builtin_amdgcn_s_sleep(1);
    }
    __syncthreads();
    if (tid == 0) WT_STORE(&bar[0], ep);
  }
  if (tid == 0) {
    while (CG_LOAD(&bar[0]) < ep) __builtin_amdgcn_s_sleep(1);
    __builtin_amdgcn_fence(__ATOMIC_ACQUIRE, "agent");
  }
  __syncthreads();
}

__global__ __launch_bounds__(NTHR, 1) void gru_persist(
    const float* __restrict__ x,
    const float* __restrict__ W0c, const float* __restrict__ U0c, const float* __restrict__ b0c,
    const float* __restrict__ W1c, const float* __restrict__ U1c, const float* __restrict__ b1c,
    const float* __restrict__ W2c, const float* __restrict__ U2c, const float* __restrict__ b2c,
    const float* __restrict__ Wd, const float* __restrict__ bd,
    float* __restrict__ out, float* __restrict__ ws)
{
  float* hbuf = ws + HBUF_OFF;
  float* ring = ws + RING_OFF;
  unsigned* bar = (unsigned*)(ws + BAR_OFF);
  float* pred_out = out;                       // [32][100][128]
  float* hid_out  = out + B_ * OUTS * D_;      // [32][100][3][512]

  const int bid = blockIdx.x;
  const int tid = threadIdx.x;

  int role, rb;
  if      (bid < 16)  { role = -1; rb = bid; }
  else if (bid < 80)  { role = 0;  rb = bid - 16; }
  else if (bid < 144) { role = 1;  rb = bid - 80; }
  else                { role = 2;  rb = bid - 144; }

  __shared__ float smem[SMEM_FLOATS];     // 126.5 KiB
  float* part = smem + PART_OFF;

  // GEMM mapping: wave = K-chunk q (tid>>6). Within wave: eg spans one 128B
  // A-row (coalesced); c_l picks the LDS weight column (A dup = free).
  const int eg  = tid & 7;
  const int c_l = (tid >> 3) & 7;
  const int q   = tid >> 6;
  // XCD-locality col swizzle
  const int cb  = (rb & 7) * 8 + (rb >> 3);
  const int c0  = cb * 8;
  // reduce/elementwise mapping (tid < 256)
  const int rc = tid >> 5;
  const int re = tid & 31;
  // LX mapping
  const int xb0 = ((rb & 7) * 2 + (rb >> 3)) * 96;
  const int cg3 = (tid & 31) * 3;
  const int e0  = (tid >> 5) * 2;

  const float *Wj = nullptr, *Ujp = nullptr, *bj = nullptr;
  if      (role == 0) { Ujp = U0c; bj = b0c; }
  else if (role == 1) { Wj = W1c; Ujp = U1c; bj = b1c; }
  else if (role == 2) { Wj = W2c; Ujp = U2c; bj = b2c; }

  // ---- one-time staging ----
  if (role < 0) {
    for (int idx = tid; idx < 128 * 96; idx += NTHR)
      smem[idx] = W0c[(idx / 96) * G3 + xb0 + (idx % 96)];
    for (int f = tid; f < 1024; f += NTHR) {
      int e = f >> 5, d4 = (f & 31) * 4;
      *(float4*)(smem + XBUF_OFF + e * 128 + d4) =
          *(const float4*)(x + e * (INS * D_) + d4);
    }
  } else {
    const int chunk = (role == 0) ? 64 : 128;
    const int chks  = (role == 0) ? W_CHK0 : W_CHK1;
    const int total = 8 * chunk * 24;
    for (int idx = tid; idx < total; idx += NTHR) {
      int qq = idx / (chunk * 24);
      int r  = idx - qq * (chunk * 24);
      int i  = r / 24;
      int cg = r - i * 24;
      int c  = cg / 3, g = cg - c * 3;
      const float* mat; int row;
      if (role == 0)      { mat = Ujp; row = qq * 64 + i; }
      else if (qq < 4)    { mat = Wj;  row = qq * 128 + i; }
      else                { mat = Ujp; row = (qq - 4) * 128 + i; }
      smem[qq * chks + (i * 8 + c) * 3 + g] = mat[row * G3 + g * 512 + c0 + c];
    }
  }
  float bz = 0.f, br = 0.f, b0h = 0.f, b1h = 0.f;
  if (role >= 0 && tid < 256) {
    const int cg2 = c0 + rc;
    bz  = bj[cg2] + bj[G3 + cg2];
    br  = bj[512 + cg2] + bj[G3 + 512 + cg2];
    b0h = bj[1024 + cg2];
    b1h = bj[G3 + 1024 + cg2];
  }
  __syncthreads();

  for (int T = 0; T < NTICK; ++T) {
    const int par_prev = (T + 1) & 1;
    const int par_cur  = T & 1;

    if (role < 0) {
      const int t = T;
      if (t < TS) {
        // (a) prefetch x(t+1) -> regs
        float4 xp0, xp1;
        const bool pf = (t + 1) < TS;
        if (pf) {
          int f0 = tid, f1 = tid + 512;
          xp0 = *(const float4*)(x + (f0 >> 5) * (INS * D_) + (t + 1) * D_ + (f0 & 31) * 4);
          xp1 = *(const float4*)(x + (f1 >> 5) * (INS * D_) + (t + 1) * D_ + (f1 & 31) * 4);
        }
        // (b) compute mx0(t) from xbuf[t&1]
        const float* xb = smem + XBUF_OFF + (t & 1) * 4096;
        float acc[3][2];
        #pragma unroll
        for (int c = 0; c < 3; ++c) { acc[c][0] = 0.f; acc[c][1] = 0.f; }
        #pragma unroll 4
        for (int k4 = 0; k4 < D_; k4 += 4) {
          float4 v0 = *(const float4*)(xb + e0 * 128 + k4);
          float4 v1 = *(const float4*)(xb + (e0 + 1) * 128 + k4);
          float xs0[4] = {v0.x, v0.y, v0.z, v0.w};
          float xs1[4] = {v1.x, v1.y, v1.z, v1.w};
          #pragma unroll
          for (int kk = 0; kk < 4; ++kk) {
            const float* wpx = smem + (k4 + kk) * 96 + cg3;
            float w0 = wpx[0], w1 = wpx[1], w2 = wpx[2];
            acc[0][0] = fmaf(xs0[kk], w0, acc[0][0]);
            acc[0][1] = fmaf(xs1[kk], w0, acc[0][1]);
            acc[1][0] = fmaf(xs0[kk], w1, acc[1][0]);
            acc[1][1] = fmaf(xs1[kk], w1, acc[1][1]);
            acc[2][0] = fmaf(xs0[kk], w2, acc[2][0]);
            acc[2][1] = fmaf(xs1[kk], w2, acc[2][1]);
          }
        }
        float* dst = ring + (t & 3) * (G3 * 32);
        #pragma unroll
        for (int c = 0; c < 3; ++c) {
          WT_STORE(dst + (xb0 + cg3 + c) * 32 + e0,     acc[c][0]);
          WT_STORE(dst + (xb0 + cg3 + c) * 32 + e0 + 1, acc[c][1]);
        }
        // (c) write prefetched x into xbuf[(t+1)&1]
        if (pf) {
          float* xw = smem + XBUF_OFF + ((t + 1) & 1) * 4096;
          int f0 = tid, f1 = tid + 512;
          *(float4*)(xw + (f0 >> 5) * 128 + (f0 & 31) * 4) = xp0;
          *(float4*)(xw + (f1 >> 5) * 128 + (f1 & 31) * 4) = xp1;
        }
      }
    } else {
      const int j = role;
      const int t = T - (j + 1);
      if (t >= 0 && t < TS) {
        const float* hprev_all = hbuf + par_prev * 49152;
        float xz = 0.f, xr2 = 0.f, xhv0 = 0.f, hp = 0.f;
        if (tid < 256) {
          const int cg2 = c0 + rc;
          hp = hprev_all[j * 16384 + cg2 * 32 + re];
          if (j == 0) {
            const float* r3 = ring + (t & 3) * (G3 * 32);
            xz   = r3[cg2 * 32 + re];
            xr2  = r3[(512 + cg2) * 32 + re];
            xhv0 = r3[(1024 + cg2) * 32 + re];
          }
        }

        float acc[3][4];
        #pragma unroll
        for (int g2 = 0; g2 < 3; ++g2)
          #pragma unroll
          for (int i2 = 0; i2 < 4; ++i2) acc[g2][i2] = 0.f;

        float4 bufA[16], bufB[16], bufC[16];
        if (j == 0) {
          const float* Ab = hprev_all + (q * 64) * 32 + eg * 4;
          const float* wp = smem + q * W_CHK0 + c_l * 3;
          LD16(bufA, Ab);        LD16(bufB, Ab + 512);
          LD16(bufC, Ab + 1024); FMA16(bufA);
          LD16(bufA, Ab + 1536); FMA16(bufB);
          FMA16(bufC);
          FMA16(bufA);
        } else {
          const int kb = (q & 3) * 128;
          const float* Ab = hprev_all + ((q < 4) ? (j - 1) : j) * 16384 + kb * 32 + eg * 4;
          const float* wp = smem + q * W_CHK1 + c_l * 3;
          LD16(bufA, Ab);        LD16(bufB, Ab + 512);
          LD16(bufC, Ab + 1024); FMA16(bufA);
          LD16(bufA, Ab + 1536); FMA16(bufB);
          LD16(bufB, Ab + 2048); FMA16(bufC);
          LD16(bufC, Ab + 2560); FMA16(bufA);
          LD16(bufA, Ab + 3072); FMA16(bufB);
          LD16(bufB, Ab + 3584); FMA16(bufC);
          FMA16(bufA);
          FMA16(bufB);
        }
        #pragma unroll
        for (int g2 = 0; g2 < 3; ++g2) {
          *(float4*)&part[PIDX3(q, g2, c_l, eg * 4)] =
              make_float4(acc[g2][0], acc[g2][1], acc[g2][2], acc[g2][3]);
        }
        __syncthreads();

        if (tid < 256) {
          float gz = 0.f, gr = 0.f, xh = 0.f, hh = 0.f;
          #pragma unroll
          for (int q2 = 0; q2 < 8; ++q2) {
            gz += part[PIDX3(q2, 0, rc, re)];
            gr += part[PIDX3(q2, 1, rc, re)];
            float v = part[PIDX3(q2, 2, rc, re)];
            if (j == 0)       hh += v;
            else if (q2 < 4)  xh += v;
            else              hh += v;
          }
          const int cg2 = c0 + rc;
          const float xhv = (j == 0) ? xhv0 : xh;
          const float zi = gz + xz + bz;
          const float ri = gr + xr2 + br;
          const float z = 1.f / (1.f + expf(-zi));
          const float r = 1.f / (1.f + expf(-ri));
          const float cand = tanhf((xhv + b0h) + r * (hh + b1h));
          const float hn = z * hp + (1.f - z) * cand;
          WT_STORE(&hbuf[par_cur * 49152 + j * 16384 + cg2 * 32 + re], hn);
          if (t >= TS - OUTS) {
            WT_STORE(&hid_out[((re * OUTS + (t - (TS - OUTS))) * 3 + j) * U_ + cg2], hn);
          }
        }
      }
    }
    gbar(bar, (unsigned)(T + 1), bid);
  }

  // readout
  const int gt = bid * NTHR + tid;
  for (int o = gt; o < B_ * OUTS * D_; o += NB * NTHR) {
    int b  = o / (OUTS * D_);
    int r2 = o - b * (OUTS * D_);
    int s  = r2 >> 7;
    int dd = r2 & 127;
    const float* ys = hid_out + ((b * OUTS + s) * 3 + 2) * U_;
    float acc = bd[dd];
    #pragma unroll 4
    for (int k = 0; k < U_; k += 4) {
      float4 yv = *(const float4*)(ys + k);
      acc = fmaf(yv.x, Wd[(k    ) * D_ + dd], acc);
      acc = fmaf(yv.y, Wd[(k + 1) * D_ + dd], acc);
      acc = fmaf(yv.z, Wd[(k + 2) * D_ + dd], acc);
      acc = fmaf(yv.w, Wd[(k + 3) * D_ + dd], acc);
    }
    pred_out[o] = acc;
  }
}

extern "C" void kernel_launch(void* const* d_in, const int* in_sizes, int n_in,
                              void* d_out, int out_size, void* d_ws, size_t ws_size,
                              hipStream_t stream) {
  const float* x  = (const float*)d_in[0];
  const float* W0 = (const float*)d_in[1];
  const float* U0 = (const float*)d_in[2];
  const float* b0 = (const float*)d_in[3];
  const float* s0 = (const float*)d_in[4];
  const float* W1 = (const float*)d_in[5];
  const float* U1 = (const float*)d_in[6];
  const float* b1 = (const float*)d_in[7];
  const float* s1 = (const float*)d_in[8];
  const float* W2 = (const float*)d_in[9];
  const float* U2 = (const float*)d_in[10];
  const float* b2 = (const float*)d_in[11];
  const float* s2 = (const float*)d_in[12];
  const float* Wd = (const float*)d_in[13];
  const float* bd = (const float*)d_in[14];
  float* ws = (float*)d_ws;

  gru_init_kernel<<<192, 256, 0, stream>>>(s0, s1, s2, ws);
  gru_persist<<<NB, NTHR, 0, stream>>>(x, W0, U0, b0, W1, U1, b1,
                                       W2, U2, b2, Wd, bd, (float*)d_out, ws);
}

// Round 10
// 10516.585 us; speedup vs baseline: 1.8794x; 1.0307x over previous
//
#include <hip/hip_runtime.h>
#include <math.h>

#define B_   32
#define INS  1000
#define TS   999           // recurrent steps (t = 0..998)
#define D_   128
#define U_   512
#define G3   1536
#define OUTS 100
#define NB   208           // 16 LX + 64 L0 + 64 L1 + 64 L2
#define NTHR 512

// ws layout (floats)
#define HBUF_OFF 0                       // [4][3][512][32]  (step&3, layer, k, e)
#define HBUF_SZ  (4*3*512*32)            // 196608
#define RING_OFF HBUF_SZ                 // [4][1536][32]    mx0 ring (step&3)
#define RING_SZ  (4*1536*32)             // 196608
#define BAR_OFF  (RING_OFF + RING_SZ)    // 4096 u32 progress slots
// slot[j*64+b] (layers), slot[192+b] (LX); each on its own 64B line (stride 16 u32)
// slot value = number of steps COMPLETED (t+1 after finishing step t)

// LDS layout (floats): same as r9
#define W_CHK1  3080
#define W_CHK0  1544
#define XBUF_OFF 12288
#define PART_OFF 24640
#define SMEM_FLOATS 32384
#define PIDX3(q,g,c,e) ((q)*968 + ((g)*8+(c))*40 + (e))

#define WT_STORE(p, v) __hip_atomic_store((p), (v), __ATOMIC_RELAXED, __HIP_MEMORY_SCOPE_AGENT)
#define CG_LOAD(p)     __hip_atomic_load((p), __ATOMIC_RELAXED, __HIP_MEMORY_SCOPE_AGENT)

#define FMA12() \
  acc[0][0]=fmaf(av.x,w0,acc[0][0]); acc[0][1]=fmaf(av.y,w0,acc[0][1]); \
  acc[0][2]=fmaf(av.z,w0,acc[0][2]); acc[0][3]=fmaf(av.w,w0,acc[0][3]); \
  acc[1][0]=fmaf(av.x,w1,acc[1][0]); acc[1][1]=fmaf(av.y,w1,acc[1][1]); \
  acc[1][2]=fmaf(av.z,w1,acc[1][2]); acc[1][3]=fmaf(av.w,w1,acc[1][3]); \
  acc[2][0]=fmaf(av.x,w2,acc[2][0]); acc[2][1]=fmaf(av.y,w2,acc[2][1]); \
  acc[2][2]=fmaf(av.z,w2,acc[2][2]); acc[2][3]=fmaf(av.w,w2,acc[2][3]);

#define LD16(DST, PTR) { _Pragma("unroll") \
  for (int t_ = 0; t_ < 16; ++t_) DST[t_] = *(const float4*)((PTR) + t_*32); }

#define FMA16(BUF) { _Pragma("unroll") \
  for (int t_ = 0; t_ < 16; ++t_) { \
    const float w0 = wp[0], w1 = wp[1], w2 = wp[2]; \
    const float4 av = BUF[t_]; \
    FMA12(); \
    wp += 24; } }

__global__ void gru_init_kernel(const float* __restrict__ s0,
                                const float* __restrict__ s1,
                                const float* __restrict__ s2,
                                float* __restrict__ ws) {
  int g = blockIdx.x * 256 + threadIdx.x;
  if (g < 4096) { unsigned* bar = (unsigned*)(ws + BAR_OFF); bar[g] = 0u; }
  // h_j(-1) lives at ring parity (-1)&3 = 3, for all layers
  for (int i = g; i < 3 * 512 * 32; i += gridDim.x * 256) {
    int which = i / (512 * 32);
    int r = i - which * (512 * 32);
    int k = r >> 5, e = r & 31;
    const float* s = (which == 0) ? s0 : ((which == 1) ? s1 : s2);
    ws[HBUF_OFF + 3 * 49152 + which * 16384 + k * 32 + e] = s[k];
  }
}

// Self-timed dependency wait. Deps for layer j at step t:
//   own   slots[j][*]   >= t    (h_j(t-1) written)
//   up    slots[j-1][*] >= t+1  (h_{j-1}(t) written)   [LX slots for j=0]
//   down  slots[j+1][*] >= t-3  (h_j(t-4) consumed; depth-4 ring slack)
// LX at step t: slots[0][*] >= t-3 (ring(t-4) consumed). Poll threads run in
// parallel (one slot each), then ONE acquire fence (L2 inv) for fresh h data.
__device__ __forceinline__ void wait_deps(unsigned* slots, int role, int t) {
  const int tid = threadIdx.x;
  const unsigned* p = nullptr; int tgt = 0;
  if (role < 0) {
    if (tid < 64)       { p = &slots[(0   + tid)       * 16]; tgt = t - 3; }
  } else if (role == 0) {
    if (tid < 64)       { p = &slots[(0   + tid)       * 16]; tgt = t;     }
    else if (tid < 80)  { p = &slots[(192 + tid - 64)  * 16]; tgt = t + 1; }
    else if (tid < 144) { p = &slots[(64  + tid - 80)  * 16]; tgt = t - 3; }
  } else if (role == 1) {
    if (tid < 64)       { p = &slots[(64  + tid)       * 16]; tgt = t;     }
    else if (tid < 128) { p = &slots[(0   + tid - 64)  * 16]; tgt = t + 1; }
    else if (tid < 192) { p = &slots[(128 + tid - 128) * 16]; tgt = t - 3; }
  } else {
    if (tid < 64)       { p = &slots[(128 + tid)       * 16]; tgt = t;     }
    else if (tid < 128) { p = &slots[(64  + tid - 64)  * 16]; tgt = t + 1; }
  }
  if (p && tgt > 0) {
    while ((int)CG_LOAD(p) < tgt) __builtin_amdgcn_s_sleep(1);
  }
  __syncthreads();
  if (role >= 0) {    // LX reads nothing cross-block -> no fence needed
    if (tid == 0) __builtin_amdgcn_fence(__ATOMIC_ACQUIRE, "agent");
    __syncthreads();
  }
}

// Publish step completion: entry __syncthreads drains vmcnt -> all WT data
// stores are at the coherence point before the slot store issues.
__device__ __forceinline__ void publish(unsigned* slots, int sidx, int t) {
  __syncthreads();
  if (threadIdx.x == 0) WT_STORE(&slots[sidx * 16], (unsigned)(t + 1));
}

__global__ __launch_bounds__(NTHR, 1) void gru_persist(
    const float* __restrict__ x,
    const float* __restrict__ W0c, const float* __restrict__ U0c, const float* __restrict__ b0c,
    const float* __restrict__ W1c, const float* __restrict__ U1c, const float* __restrict__ b1c,
    const float* __restrict__ W2c, const float* __restrict__ U2c, const float* __restrict__ b2c,
    const float* __restrict__ Wd, const float* __restrict__ bd,
    float* __restrict__ out, float* __restrict__ ws)
{
  float* hbuf = ws + HBUF_OFF;
  float* ring = ws + RING_OFF;
  unsigned* slots = (unsigned*)(ws + BAR_OFF);
  float* pred_out = out;                       // [32][100][128]
  float* hid_out  = out + B_ * OUTS * D_;      // [32][100][3][512]

  const int bid = blockIdx.x;
  const int tid = threadIdx.x;

  int role, rb;
  if      (bid < 16)  { role = -1; rb = bid; }
  else if (bid < 80)  { role = 0;  rb = bid - 16; }
  else if (bid < 144) { role = 1;  rb = bid - 80; }
  else                { role = 2;  rb = bid - 144; }
  const int sidx = (role < 0) ? (192 + rb) : (role * 64 + rb);

  __shared__ float smem[SMEM_FLOATS];     // 126.5 KiB
  float* part = smem + PART_OFF;

  const int eg  = tid & 7;
  const int c_l = (tid >> 3) & 7;
  const int q   = tid >> 6;
  const int cb  = (rb & 7) * 8 + (rb >> 3);
  const int c0  = cb * 8;
  const int rc = tid >> 5;
  const int re = tid & 31;
  const int xb0 = ((rb & 7) * 2 + (rb >> 3)) * 96;
  const int cg3 = (tid & 31) * 3;
  const int e0  = (tid >> 5) * 2;

  const float *Wj = nullptr, *Ujp = nullptr, *bj = nullptr;
  if      (role == 0) { Ujp = U0c; bj = b0c; }
  else if (role == 1) { Wj = W1c; Ujp = U1c; bj = b1c; }
  else if (role == 2) { Wj = W2c; Ujp = U2c; bj = b2c; }

  // ---- one-time staging (r9 verbatim) ----
  if (role < 0) {
    for (int idx = tid; idx < 128 * 96; idx += NTHR)
      smem[idx] = W0c[(idx / 96) * G3 + xb0 + (idx % 96)];
    for (int f = tid; f < 1024; f += NTHR) {
      int e = f >> 5, d4 = (f & 31) * 4;
      *(float4*)(smem + XBUF_OFF + e * 128 + d4) =
          *(const float4*)(x + e * (INS * D_) + d4);
    }
  } else {
    const int chunk = (role == 0) ? 64 : 128;
    const int chks  = (role == 0) ? W_CHK0 : W_CHK1;
    const int total = 8 * chunk * 24;
    for (int idx = tid; idx < total; idx += NTHR) {
      int qq = idx / (chunk * 24);
      int r  = idx - qq * (chunk * 24);
      int i  = r / 24;
      int cg = r - i * 24;
      int c  = cg / 3, g = cg - c * 3;
      const float* mat; int row;
      if (role == 0)      { mat = Ujp; row = qq * 64 + i; }
      else if (qq < 4)    { mat = Wj;  row = qq * 128 + i; }
      else                { mat = Ujp; row = (qq - 4) * 128 + i; }
      smem[qq * chks + (i * 8 + c) * 3 + g] = mat[row * G3 + g * 512 + c0 + c];
    }
  }
  float bz = 0.f, br = 0.f, b0h = 0.f, b1h = 0.f;
  if (role >= 0 && tid < 256) {
    const int cg2 = c0 + rc;
    bz  = bj[cg2] + bj[G3 + cg2];
    br  = bj[512 + cg2] + bj[G3 + 512 + cg2];
    b0h = bj[1024 + cg2];
    b1h = bj[G3 + 1024 + cg2];
  }
  __syncthreads();

  // ---- self-timed step loop: each block runs its OWN t = 0..TS-1 ----
  for (int t = 0; t < TS; ++t) {
    wait_deps(slots, role, t);

    if (role < 0) {
      // LX: mx0(t) = x_t @ W0 -> ring[t&3]; prefetch x(t+1) -> xbuf
      float4 xp0, xp1;
      const bool pf = (t + 1) < TS;
      if (pf) {
        int f0 = tid, f1 = tid + 512;
        xp0 = *(const float4*)(x + (f0 >> 5) * (INS * D_) + (t + 1) * D_ + (f0 & 31) * 4);
        xp1 = *(const float4*)(x + (f1 >> 5) * (INS * D_) + (t + 1) * D_ + (f1 & 31) * 4);
      }
      const float* xb = smem + XBUF_OFF + (t & 1) * 4096;
      float acc[3][2];
      #pragma unroll
      for (int c = 0; c < 3; ++c) { acc[c][0] = 0.f; acc[c][1] = 0.f; }
      #pragma unroll 4
      for (int k4 = 0; k4 < D_; k4 += 4) {
        float4 v0 = *(const float4*)(xb + e0 * 128 + k4);
        float4 v1 = *(const float4*)(xb + (e0 + 1) * 128 + k4);
        float xs0[4] = {v0.x, v0.y, v0.z, v0.w};
        float xs1[4] = {v1.x, v1.y, v1.z, v1.w};
        #pragma unroll
        for (int kk = 0; kk < 4; ++kk) {
          const float* wpx = smem + (k4 + kk) * 96 + cg3;
          float w0 = wpx[0], w1 = wpx[1], w2 = wpx[2];
          acc[0][0] = fmaf(xs0[kk], w0, acc[0][0]);
          acc[0][1] = fmaf(xs1[kk], w0, acc[0][1]);
          acc[1][0] = fmaf(xs0[kk], w1, acc[1][0]);
          acc[1][1] = fmaf(xs1[kk], w1, acc[1][1]);
          acc[2][0] = fmaf(xs0[kk], w2, acc[2][0]);
          acc[2][1] = fmaf(xs1[kk], w2, acc[2][1]);
        }
      }
      float* dst = ring + (t & 3) * (G3 * 32);
      #pragma unroll
      for (int c = 0; c < 3; ++c) {
        WT_STORE(dst + (xb0 + cg3 + c) * 32 + e0,     acc[c][0]);
        WT_STORE(dst + (xb0 + cg3 + c) * 32 + e0 + 1, acc[c][1]);
      }
      if (pf) {
        float* xw = smem + XBUF_OFF + ((t + 1) & 1) * 4096;
        int f0 = tid, f1 = tid + 512;
        *(float4*)(xw + (f0 >> 5) * 128 + (f0 & 31) * 4) = xp0;
        *(float4*)(xw + (f1 >> 5) * 128 + (f1 & 31) * 4) = xp1;
      }
    } else {
      const int j = role;
      const float* hown = hbuf + ((t + 3) & 3) * 49152;   // h(t-1) parity
      const float* hup  = hbuf + (t & 3) * 49152;         // h_{j-1}(t) parity
      float xz = 0.f, xr2 = 0.f, xhv0 = 0.f, hp = 0.f;
      if (tid < 256) {
        const int cg2 = c0 + rc;
        hp = hown[j * 16384 + cg2 * 32 + re];
        if (j == 0) {
          const float* r3 = ring + (t & 3) * (G3 * 32);
          xz   = r3[cg2 * 32 + re];
          xr2  = r3[(512 + cg2) * 32 + re];
          xhv0 = r3[(1024 + cg2) * 32 + re];
        }
      }

      float acc[3][4];
      #pragma unroll
      for (int g2 = 0; g2 < 3; ++g2)
        #pragma unroll
        for (int i2 = 0; i2 < 4; ++i2) acc[g2][i2] = 0.f;

      float4 bufA[16], bufB[16], bufC[16];
      if (j == 0) {
        const float* Ab = hown + (q * 64) * 32 + eg * 4;   // h0(t-1)
        const float* wp = smem + q * W_CHK0 + c_l * 3;
        LD16(bufA, Ab);        LD16(bufB, Ab + 512);
        LD16(bufC, Ab + 1024); FMA16(bufA);
        LD16(bufA, Ab + 1536); FMA16(bufB);
        FMA16(bufC);
        FMA16(bufA);
      } else {
        const int kb = (q & 3) * 128;
        // q<4: x-side = h_{j-1}(t) (hup); q>=4: h-side = h_j(t-1) (hown)
        const float* Ab = ((q < 4) ? (hup + (j - 1) * 16384) : (hown + j * 16384))
                          + kb * 32 + eg * 4;
        const float* wp = smem + q * W_CHK1 + c_l * 3;
        LD16(bufA, Ab);        LD16(bufB, Ab + 512);
        LD16(bufC, Ab + 1024); FMA16(bufA);
        LD16(bufA, Ab + 1536); FMA16(bufB);
        LD16(bufB, Ab + 2048); FMA16(bufC);
        LD16(bufC, Ab + 2560); FMA16(bufA);
        LD16(bufA, Ab + 3072); FMA16(bufB);
        LD16(bufB, Ab + 3584); FMA16(bufC);
        FMA16(bufA);
        FMA16(bufB);
      }
      #pragma unroll
      for (int g2 = 0; g2 < 3; ++g2) {
        *(float4*)&part[PIDX3(q, g2, c_l, eg * 4)] =
            make_float4(acc[g2][0], acc[g2][1], acc[g2][2], acc[g2][3]);
      }
      __syncthreads();

      if (tid < 256) {
        float gz = 0.f, gr = 0.f, xh = 0.f, hh = 0.f;
        #pragma unroll
        for (int q2 = 0; q2 < 8; ++q2) {
          gz += part[PIDX3(q2, 0, rc, re)];
          gr += part[PIDX3(q2, 1, rc, re)];
          float v = part[PIDX3(q2, 2, rc, re)];
          if (j == 0)       hh += v;
          else if (q2 < 4)  xh += v;
          else              hh += v;
        }
        const int cg2 = c0 + rc;
        const float xhv = (j == 0) ? xhv0 : xh;
        const float zi = gz + xz + bz;
        const float ri = gr + xr2 + br;
        const float z = 1.f / (1.f + expf(-zi));
        const float r = 1.f / (1.f + expf(-ri));
        const float cand = tanhf((xhv + b0h) + r * (hh + b1h));
        const float hn = z * hp + (1.f - z) * cand;
        WT_STORE(&hbuf[(t & 3) * 49152 + j * 16384 + cg2 * 32 + re], hn);
        if (t >= TS - OUTS) {
          WT_STORE(&hid_out[((re * OUTS + (t - (TS - OUTS))) * 3 + j) * U_ + cg2], hn);
        }
      }
    }
    publish(slots, sidx, t);
  }

  // ---- readout: wait for L2 completion, one acquire, then pred ----
  if (tid < 64) {
    while ((int)CG_LOAD(&slots[(128 + tid) * 16]) < TS) __builtin_amdgcn_s_sleep(1);
  }
  __syncthreads();
  if (tid == 0) __builtin_amdgcn_fence(__ATOMIC_ACQUIRE, "agent");
  __syncthreads();

  const int gt = bid * NTHR + tid;
  for (int o = gt; o < B_ * OUTS * D_; o += NB * NTHR) {
    int b  = o / (OUTS * D_);
    int r2 = o - b * (OUTS * D_);
    int s  = r2 >> 7;
    int dd = r2 & 127;
    const float* ys = hid_out + ((b * OUTS + s) * 3 + 2) * U_;
    float acc = bd[dd];
    #pragma unroll 4
    for (int k = 0; k < U_; k += 4) {
      float4 yv = *(const float4*)(ys + k);
      acc = fmaf(yv.x, Wd[(k    ) * D_ + dd], acc);
      acc = fmaf(yv.y, Wd[(k + 1) * D_ + dd], acc);
      acc = fmaf(yv.z, Wd[(k + 2) * D_ + dd], acc);
      acc = fmaf(yv.w, Wd[(k + 3) * D_ + dd], acc);
    }
    pred_out[o] = acc;
  }
}

extern "C" void kernel_launch(void* const* d_in, const int* in_sizes, int n_in,
                              void* d_out, int out_size, void* d_ws, size_t ws_size,
                              hipStream_t stream) {
  const float* x  = (const float*)d_in[0];
  const float* W0 = (const float*)d_in[1];
  const float* U0 = (const float*)d_in[2];
  const float* b0 = (const float*)d_in[3];
  const float* s0 = (const float*)d_in[4];
  const float* W1 = (const float*)d_in[5];
  const float* U1 = (const float*)d_in[6];
  const float* b1 = (const float*)d_in[7];
  const float* s1 = (const float*)d_in[8];
  const float* W2 = (const float*)d_in[9];
  const float* U2 = (const float*)d_in[10];
  const float* b2 = (const float*)d_in[11];
  const float* s2 = (const float*)d_in[12];
  const float* Wd = (const float*)d_in[13];
  const float* bd = (const float*)d_in[14];
  float* ws = (float*)d_ws;

  gru_init_kernel<<<192, 256, 0, stream>>>(s0, s1, s2, ws);
  gru_persist<<<NB, NTHR, 0, stream>>>(x, W0, U0, b0, W1, U1, b1,
                                       W2, U2, b2, Wd, bd, (float*)d_out, ws);
}